// Round 4
// baseline (1053.670 us; speedup 1.0000x reference)
//
#include <hip/hip_runtime.h>

// Problem dims (fixed by reference)
#define INN 9    // 2*L+1
#define FCN 18
#define HN  18
#define LN  4

__device__ __forceinline__ float rcp_f(float x) { return __builtin_amdgcn_rcpf(x); }
__device__ __forceinline__ float sigm(float x)  { return rcp_f(1.0f + __expf(-x)); }
__device__ __forceinline__ float tanh_f(float x) {
    // tanh(x) = (e^{2x}-1)/(e^{2x}+1); clamp to avoid inf/inf NaN (saturates anyway)
    float t = __expf(fminf(2.0f * x, 80.0f));
    return (t - 1.0f) * rcp_f(t + 1.0f);
}

// Two GRU cells sharing one j-loop so g[j] = oA + sign*oB can be folded into the
// mask-layer accumulator immediately (no runtime-indexed register arrays -> no scratch).
// Cell A: (yA, hA, weightsA). Cell B: (yB, hB, weightsB).
__device__ __forceinline__ void cell_pair(
    const float* yA, const float* yB,            // [FCN] register arrays
    const float* hAreg, const float* hBreg,      // [HN] register arrays
    const float* __restrict__ hAg, const float* __restrict__ hBg,   // global rows (b*HN)
    const float* __restrict__ WihA, const float* __restrict__ WhhA,
    const float* __restrict__ bihA, const float* __restrict__ bhhA,
    const float* __restrict__ WihB, const float* __restrict__ WhhB,
    const float* __restrict__ bihB, const float* __restrict__ bhhB,
    float* __restrict__ outAg, float* __restrict__ outBg,           // global rows (b*HN)
    const float* __restrict__ Wm,                // (FCN,HN) row-major, column j read
    float sign, float* macc)                     // [FCN] register accumulator
{
    // Rolled j-loop: ~280 insts/iter, keeps I$ footprint ~10KB. All weight/bias
    // addresses are wave-uniform -> s_load; h[j] re-read from global (L1-hot).
    #pragma unroll 1
    for (int j = 0; j < HN; ++j) {
        float aIr = bihA[j], aIz = bihA[HN + j], aIn = bihA[2 * HN + j];
        float aHr = bhhA[j], aHz = bhhA[HN + j], aHn = bhhA[2 * HN + j];
        float bIr = bihB[j], bIz = bihB[HN + j], bIn = bihB[2 * HN + j];
        float bHr = bhhB[j], bHz = bhhB[HN + j], bHn = bhhB[2 * HN + j];

        const float* wA0 = WihA + j * FCN;
        const float* wA1 = WihA + (HN + j) * FCN;
        const float* wA2 = WihA + (2 * HN + j) * FCN;
        const float* wB0 = WihB + j * FCN;
        const float* wB1 = WihB + (HN + j) * FCN;
        const float* wB2 = WihB + (2 * HN + j) * FCN;
        #pragma unroll
        for (int k = 0; k < FCN; ++k) {
            aIr = fmaf(yA[k], wA0[k], aIr);
            aIz = fmaf(yA[k], wA1[k], aIz);
            aIn = fmaf(yA[k], wA2[k], aIn);
            bIr = fmaf(yB[k], wB0[k], bIr);
            bIz = fmaf(yB[k], wB1[k], bIz);
            bIn = fmaf(yB[k], wB2[k], bIn);
        }

        const float* uA0 = WhhA + j * HN;
        const float* uA1 = WhhA + (HN + j) * HN;
        const float* uA2 = WhhA + (2 * HN + j) * HN;
        const float* uB0 = WhhB + j * HN;
        const float* uB1 = WhhB + (HN + j) * HN;
        const float* uB2 = WhhB + (2 * HN + j) * HN;
        #pragma unroll
        for (int k = 0; k < HN; ++k) {
            aHr = fmaf(hAreg[k], uA0[k], aHr);
            aHz = fmaf(hAreg[k], uA1[k], aHz);
            aHn = fmaf(hAreg[k], uA2[k], aHn);
            bHr = fmaf(hBreg[k], uB0[k], bHr);
            bHz = fmaf(hBreg[k], uB1[k], bHz);
            bHn = fmaf(hBreg[k], uB2[k], bHn);
        }

        float rA = sigm(aIr + aHr);
        float zA = sigm(aIz + aHz);
        float nA = tanh_f(aIn + rA * aHn);
        float hjA = hAg[j];                       // runtime j -> global reload (L1 hit)
        float oA = (1.0f - zA) * nA + zA * hjA;

        float rB = sigm(bIr + bHr);
        float zB = sigm(bIz + bHz);
        float nB = tanh_f(bIn + rB * bHn);
        float hjB = hBg[j];
        float oB = (1.0f - zB) * nB + zB * hjB;

        outAg[j] = oA;                            // these ARE outputs (Frr/Fir/Fri/Fii)
        outBg[j] = oB;

        float g = oA + sign * oB;                 // g_real (sign=-1) / g_imag (sign=+1)
        #pragma unroll
        for (int i = 0; i < FCN; ++i)             // mask layer folded in: macc += g * Wm[:,j]
            macc[i] = fmaf(g, Wm[i * HN + j], macc[i]);
    }
}

__global__ __launch_bounds__(256) void kgnet_kernel(
    const float* __restrict__ in_r, const float* __restrict__ in_i,
    const float* __restrict__ h_rr, const float* __restrict__ h_ir,
    const float* __restrict__ h_ri, const float* __restrict__ h_ii,
    const float* __restrict__ Wr_in, const float* __restrict__ br_in,
    const float* __restrict__ Wi_in, const float* __restrict__ bi_in,
    const float* __restrict__ a1p,
    const float* __restrict__ gr_Wih, const float* __restrict__ gr_Whh,
    const float* __restrict__ gr_bih, const float* __restrict__ gr_bhh,
    const float* __restrict__ gi_Wih, const float* __restrict__ gi_Whh,
    const float* __restrict__ gi_bih, const float* __restrict__ gi_bhh,
    const float* __restrict__ Wr_m, const float* __restrict__ br_m,
    const float* __restrict__ Wi_m, const float* __restrict__ bi_m,
    const float* __restrict__ a2p,
    const float* __restrict__ Wr_o, const float* __restrict__ br_o,
    const float* __restrict__ Wi_o, const float* __restrict__ bi_o,
    float* __restrict__ out, int n)
{
    int b = blockIdx.x * blockDim.x + threadIdx.x;
    if (b >= n) return;
    const float a1 = a1p[0];
    const float a2 = a2p[0];

    // ---- input layer: yr/yi = prelu(x @ W_in.T + b_in) ----
    float xr[INN], xi[INN];
    #pragma unroll
    for (int k = 0; k < INN; ++k) {
        xr[k] = in_r[(size_t)b * INN + k];
        xi[k] = in_i[(size_t)b * INN + k];
    }
    float yr[FCN], yi[FCN];
    #pragma unroll
    for (int j = 0; j < FCN; ++j) {
        float sr = br_in[j], si = bi_in[j];
        #pragma unroll
        for (int k = 0; k < INN; ++k) {
            sr = fmaf(xr[k], Wr_in[j * INN + k], sr);
            si = fmaf(xi[k], Wi_in[j * INN + k], si);
        }
        yr[j] = sr >= 0.0f ? sr : a1 * sr;
        yi[j] = si >= 0.0f ? si : a1 * si;
    }

    // ---- output regions: [kr B*4][ki B*4][Frr B*18][Fir][Fri][Fii] ----
    const size_t B = (size_t)n;
    float* o_kr  = out;
    float* o_ki  = out + 4 * B;
    float* outF  = out + 8 * B;
    float* o_frr = outF + (size_t)b * HN;
    float* o_fir = outF + B * HN + (size_t)b * HN;
    float* o_fri = outF + 2 * B * HN + (size_t)b * HN;
    float* o_fii = outF + 3 * B * HN + (size_t)b * HN;

    const float* prr = h_rr + (size_t)b * HN;
    const float* pir = h_ir + (size_t)b * HN;
    const float* pri = h_ri + (size_t)b * HN;
    const float* pii = h_ii + (size_t)b * HN;

    float mr_acc[FCN], mi_acc[FCN];
    #pragma unroll
    for (int i = 0; i < FCN; ++i) { mr_acc[i] = 0.0f; mi_acc[i] = 0.0f; }

    // ---- pair 1: Frr (yr,h_rr,gr) & Fii (yi,h_ii,gi); g_real = Frr - Fii ----
    {
        float hA[HN], hB[HN];
        #pragma unroll
        for (int k = 0; k < HN; ++k) { hA[k] = prr[k]; hB[k] = pii[k]; }
        cell_pair(yr, yi, hA, hB, prr, pii,
                  gr_Wih, gr_Whh, gr_bih, gr_bhh,
                  gi_Wih, gi_Whh, gi_bih, gi_bhh,
                  o_frr, o_fii, Wr_m, -1.0f, mr_acc);
    }
    // ---- pair 2: Fir (yi,h_ir,gr) & Fri (yr,h_ri,gi); g_imag = Fir + Fri ----
    {
        float hA[HN], hB[HN];
        #pragma unroll
        for (int k = 0; k < HN; ++k) { hA[k] = pir[k]; hB[k] = pri[k]; }
        cell_pair(yi, yr, hA, hB, pir, pri,
                  gr_Wih, gr_Whh, gr_bih, gr_bhh,
                  gi_Wih, gi_Whh, gi_bih, gi_bhh,
                  o_fir, o_fri, Wi_m, +1.0f, mi_acc);
    }

    // ---- mask prelu + output layer ----
    float kr[LN], ki[LN];
    #pragma unroll
    for (int l = 0; l < LN; ++l) { kr[l] = br_o[l]; ki[l] = bi_o[l]; }
    #pragma unroll
    for (int j = 0; j < FCN; ++j) {
        float mr = mr_acc[j] + br_m[j];
        mr = mr >= 0.0f ? mr : a2 * mr;
        float mi = mi_acc[j] + bi_m[j];
        mi = mi >= 0.0f ? mi : a2 * mi;
        #pragma unroll
        for (int l = 0; l < LN; ++l) {
            kr[l] = fmaf(mr, Wr_o[l * FCN + j], kr[l]);
            ki[l] = fmaf(mi, Wi_o[l * FCN + j], ki[l]);
        }
    }
    *(reinterpret_cast<float4*>(o_kr) + b) = make_float4(kr[0], kr[1], kr[2], kr[3]);
    *(reinterpret_cast<float4*>(o_ki) + b) = make_float4(ki[0], ki[1], ki[2], ki[3]);
}

extern "C" void kernel_launch(void* const* d_in, const int* in_sizes, int n_in,
                              void* d_out, int out_size, void* d_ws, size_t ws_size,
                              hipStream_t stream) {
    const int n = in_sizes[0] / INN;   // batch size (524288)
    const float* in_r   = (const float*)d_in[0];
    const float* in_i   = (const float*)d_in[1];
    const float* h_rr   = (const float*)d_in[2];
    const float* h_ir   = (const float*)d_in[3];
    const float* h_ri   = (const float*)d_in[4];
    const float* h_ii   = (const float*)d_in[5];
    const float* Wr_in  = (const float*)d_in[6];
    const float* br_in  = (const float*)d_in[7];
    const float* Wi_in  = (const float*)d_in[8];
    const float* bi_in  = (const float*)d_in[9];
    const float* a1p    = (const float*)d_in[10];
    const float* gr_Wih = (const float*)d_in[11];
    const float* gr_Whh = (const float*)d_in[12];
    const float* gr_bih = (const float*)d_in[13];
    const float* gr_bhh = (const float*)d_in[14];
    const float* gi_Wih = (const float*)d_in[15];
    const float* gi_Whh = (const float*)d_in[16];
    const float* gi_bih = (const float*)d_in[17];
    const float* gi_bhh = (const float*)d_in[18];
    const float* Wr_m   = (const float*)d_in[19];
    const float* br_m   = (const float*)d_in[20];
    const float* Wi_m   = (const float*)d_in[21];
    const float* bi_m   = (const float*)d_in[22];
    const float* a2p    = (const float*)d_in[23];
    const float* Wr_o   = (const float*)d_in[24];
    const float* br_o   = (const float*)d_in[25];
    const float* Wi_o   = (const float*)d_in[26];
    const float* bi_o   = (const float*)d_in[27];

    dim3 block(256);
    dim3 grid((n + 255) / 256);
    kgnet_kernel<<<grid, block, 0, stream>>>(
        in_r, in_i, h_rr, h_ir, h_ri, h_ii,
        Wr_in, br_in, Wi_in, bi_in, a1p,
        gr_Wih, gr_Whh, gr_bih, gr_bhh,
        gi_Wih, gi_Whh, gi_bih, gi_bhh,
        Wr_m, br_m, Wi_m, bi_m, a2p,
        Wr_o, br_o, Wi_o, bi_o,
        (float*)d_out, n);
}

// Round 8
// 722.122 us; speedup vs baseline: 1.4591x; 1.4591x over previous
//
#include <hip/hip_runtime.h>

// Problem dims (fixed by reference)
#define INN 9    // 2*L+1
#define FCN 18
#define HN  18
#define LN  4

__device__ __forceinline__ float rcp_f(float x) { return __builtin_amdgcn_rcpf(x); }
__device__ __forceinline__ float sigm(float x)  { return rcp_f(1.0f + __expf(-x)); }
__device__ __forceinline__ float tanh_f(float x) {
    float t = __expf(fminf(2.0f * x, 80.0f));
    return (t - 1.0f) * rcp_f(t + 1.0f);
}

// Coalesced float2 staging: 64 rows x 18 floats = 576 float2, 9 per lane.
// g must point at the wave's region start (8B-aligned: waveBase*72 bytes).
__device__ __forceinline__ void stage2(float* __restrict__ buf, const float* __restrict__ g, int lane) {
    const float2* g2 = reinterpret_cast<const float2*>(g);
    float2* l2 = reinterpret_cast<float2*>(buf);
    #pragma unroll
    for (int t = 0; t < 9; ++t) l2[lane + 64 * t] = g2[lane + 64 * t];
}
__device__ __forceinline__ void store2(float* __restrict__ g, const float* __restrict__ buf, int lane) {
    float2* g2 = reinterpret_cast<float2*>(g);
    const float2* l2 = reinterpret_cast<const float2*>(buf);
    #pragma unroll
    for (int t = 0; t < 9; ++t) g2[lane + 64 * t] = l2[lane + 64 * t];
}

// Two GRU cells sharing one j-loop. h rows live in wave-private LDS (lA/lB point
// at this lane's 18-float row); slot j is read (h[j]) then overwritten in place
// with the cell output o[j] — the buffer morphs h -> F for the coalesced store.
// g[j] = oA + sign*oB folds immediately into the mask accumulator (no
// runtime-indexed register arrays -> no scratch).
__device__ __forceinline__ void cell_pair(
    const float* yA, const float* yB,            // [FCN] register arrays
    const float* hAreg, const float* hBreg,      // [HN] register arrays
    float* lA, float* lB,                        // LDS row ptrs (lane-private)
    const float* __restrict__ WihA, const float* __restrict__ WhhA,
    const float* __restrict__ bihA, const float* __restrict__ bhhA,
    const float* __restrict__ WihB, const float* __restrict__ WhhB,
    const float* __restrict__ bihB, const float* __restrict__ bhhB,
    const float* __restrict__ Wm,                // (FCN,HN) row-major, column j read
    float sign, float* macc)                     // [FCN] register accumulator
{
    #pragma unroll 1
    for (int j = 0; j < HN; ++j) {
        float aIr = bihA[j], aIz = bihA[HN + j], aIn = bihA[2 * HN + j];
        float aHr = bhhA[j], aHz = bhhA[HN + j], aHn = bhhA[2 * HN + j];
        float bIr = bihB[j], bIz = bihB[HN + j], bIn = bihB[2 * HN + j];
        float bHr = bhhB[j], bHz = bhhB[HN + j], bHn = bhhB[2 * HN + j];

        const float* wA0 = WihA + j * FCN;
        const float* wA1 = WihA + (HN + j) * FCN;
        const float* wA2 = WihA + (2 * HN + j) * FCN;
        const float* wB0 = WihB + j * FCN;
        const float* wB1 = WihB + (HN + j) * FCN;
        const float* wB2 = WihB + (2 * HN + j) * FCN;
        #pragma unroll
        for (int k = 0; k < FCN; ++k) {
            aIr = fmaf(yA[k], wA0[k], aIr);
            aIz = fmaf(yA[k], wA1[k], aIz);
            aIn = fmaf(yA[k], wA2[k], aIn);
            bIr = fmaf(yB[k], wB0[k], bIr);
            bIz = fmaf(yB[k], wB1[k], bIz);
            bIn = fmaf(yB[k], wB2[k], bIn);
        }

        const float* uA0 = WhhA + j * HN;
        const float* uA1 = WhhA + (HN + j) * HN;
        const float* uA2 = WhhA + (2 * HN + j) * HN;
        const float* uB0 = WhhB + j * HN;
        const float* uB1 = WhhB + (HN + j) * HN;
        const float* uB2 = WhhB + (2 * HN + j) * HN;
        #pragma unroll
        for (int k = 0; k < HN; ++k) {
            aHr = fmaf(hAreg[k], uA0[k], aHr);
            aHz = fmaf(hAreg[k], uA1[k], aHz);
            aHn = fmaf(hAreg[k], uA2[k], aHn);
            bHr = fmaf(hBreg[k], uB0[k], bHr);
            bHz = fmaf(hBreg[k], uB1[k], bHz);
            bHn = fmaf(hBreg[k], uB2[k], bHn);
        }

        float rA = sigm(aIr + aHr);
        float zA = sigm(aIz + aHz);
        float nA = tanh_f(aIn + rA * aHn);
        float hjA = lA[j];                        // LDS, runtime j: fine
        float oA = (1.0f - zA) * nA + zA * hjA;

        float rB = sigm(bIr + bHr);
        float zB = sigm(bIz + bHz);
        float nB = tanh_f(bIn + rB * bHn);
        float hjB = lB[j];
        float oB = (1.0f - zB) * nB + zB * hjB;

        lA[j] = oA;                               // in-place: h row becomes F row
        lB[j] = oB;

        float g = oA + sign * oB;                 // g_real (sign=-1) / g_imag (sign=+1)
        #pragma unroll
        for (int i = 0; i < FCN; ++i)
            macc[i] = fmaf(g, Wm[i * HN + j], macc[i]);
    }
}

__global__ __launch_bounds__(256) void kgnet_kernel(
    const float* __restrict__ in_r, const float* __restrict__ in_i,
    const float* __restrict__ h_rr, const float* __restrict__ h_ir,
    const float* __restrict__ h_ri, const float* __restrict__ h_ii,
    const float* __restrict__ Wr_in, const float* __restrict__ br_in,
    const float* __restrict__ Wi_in, const float* __restrict__ bi_in,
    const float* __restrict__ a1p,
    const float* __restrict__ gr_Wih, const float* __restrict__ gr_Whh,
    const float* __restrict__ gr_bih, const float* __restrict__ gr_bhh,
    const float* __restrict__ gi_Wih, const float* __restrict__ gi_Whh,
    const float* __restrict__ gi_bih, const float* __restrict__ gi_bhh,
    const float* __restrict__ Wr_m, const float* __restrict__ br_m,
    const float* __restrict__ Wi_m, const float* __restrict__ bi_m,
    const float* __restrict__ a2p,
    const float* __restrict__ Wr_o, const float* __restrict__ br_o,
    const float* __restrict__ Wi_o, const float* __restrict__ bi_o,
    float* __restrict__ out, int n)
{
    // Wave-private staging buffers: [wave][2][64*18] floats = 36,864 B / block.
    // All LDS traffic is within-wave -> no __syncthreads needed anywhere.
    __shared__ float lds[4][2][64 * HN];

    const int tid  = threadIdx.x;
    const int wave = tid >> 6;
    const int lane = tid & 63;
    const int waveBase = blockIdx.x * 256 + (wave << 6);
    if (waveBase >= n) return;                    // wave-uniform (n % 64 == 0)
    const int b = waveBase + lane;

    float* bufA = lds[wave][0];
    float* bufB = lds[wave][1];

    const float a1 = a1p[0];
    const float a2 = a2p[0];

    // ---- stage inputs coalesced into bufA: in_r at [0,576), in_i at [576,1152) ----
    {
        const float* gr_ = in_r + (size_t)waveBase * INN;
        const float* gi_ = in_i + (size_t)waveBase * INN;
        #pragma unroll
        for (int t = 0; t < INN; ++t) {
            bufA[lane + 64 * t]       = gr_[lane + 64 * t];
            bufA[576 + lane + 64 * t] = gi_[lane + 64 * t];
        }
    }

    // ---- input layer: yr/yi = prelu(x @ W_in.T + b_in) ----
    float yr[FCN], yi[FCN];
    {
        float xr[INN], xi[INN];
        const float* rowr = bufA + lane * INN;
        const float* rowi = bufA + 576 + lane * INN;
        #pragma unroll
        for (int k = 0; k < INN; ++k) { xr[k] = rowr[k]; xi[k] = rowi[k]; }
        #pragma unroll
        for (int j = 0; j < FCN; ++j) {
            float sr = br_in[j], si = bi_in[j];
            #pragma unroll
            for (int k = 0; k < INN; ++k) {
                sr = fmaf(xr[k], Wr_in[j * INN + k], sr);
                si = fmaf(xi[k], Wi_in[j * INN + k], si);
            }
            yr[j] = sr >= 0.0f ? sr : a1 * sr;
            yi[j] = si >= 0.0f ? si : a1 * si;
        }
    }

    // ---- output regions: [kr B*4][ki B*4][Frr B*18][Fir][Fri][Fii] ----
    const size_t B = (size_t)n;
    float* o_kr = out;
    float* o_ki = out + 4 * B;
    float* outF = out + 8 * B;
    const size_t woff = (size_t)waveBase * HN;    // wave's F/h region offset (floats)

    float mr_acc[FCN], mi_acc[FCN];
    #pragma unroll
    for (int i = 0; i < FCN; ++i) { mr_acc[i] = 0.0f; mi_acc[i] = 0.0f; }

    float* lA = bufA + lane * HN;
    float* lB = bufB + lane * HN;

    // ---- pair 1: Frr (yr,h_rr,gr) & Fii (yi,h_ii,gi); g_real = Frr - Fii ----
    {
        stage2(bufA, h_rr + woff, lane);
        stage2(bufB, h_ii + woff, lane);
        float hA[HN], hB[HN];
        #pragma unroll
        for (int k = 0; k < HN; ++k) { hA[k] = lA[k]; hB[k] = lB[k]; }
        cell_pair(yr, yi, hA, hB, lA, lB,
                  gr_Wih, gr_Whh, gr_bih, gr_bhh,
                  gi_Wih, gi_Whh, gi_bih, gi_bhh,
                  Wr_m, -1.0f, mr_acc);
        store2(outF + 0 * B * HN + woff, bufA, lane);   // Frr
        store2(outF + 3 * B * HN + woff, bufB, lane);   // Fii
    }
    // ---- pair 2: Fir (yi,h_ir,gr) & Fri (yr,h_ri,gi); g_imag = Fir + Fri ----
    {
        stage2(bufA, h_ir + woff, lane);
        stage2(bufB, h_ri + woff, lane);
        float hA[HN], hB[HN];
        #pragma unroll
        for (int k = 0; k < HN; ++k) { hA[k] = lA[k]; hB[k] = lB[k]; }
        cell_pair(yi, yr, hA, hB, lA, lB,
                  gr_Wih, gr_Whh, gr_bih, gr_bhh,
                  gi_Wih, gi_Whh, gi_bih, gi_bhh,
                  Wi_m, +1.0f, mi_acc);
        store2(outF + 1 * B * HN + woff, bufA, lane);   // Fir
        store2(outF + 2 * B * HN + woff, bufB, lane);   // Fri
    }

    // ---- mask prelu + output layer ----
    float kr[LN], ki[LN];
    #pragma unroll
    for (int l = 0; l < LN; ++l) { kr[l] = br_o[l]; ki[l] = bi_o[l]; }
    #pragma unroll
    for (int j = 0; j < FCN; ++j) {
        float mr = mr_acc[j] + br_m[j];
        mr = mr >= 0.0f ? mr : a2 * mr;
        float mi = mi_acc[j] + bi_m[j];
        mi = mi >= 0.0f ? mi : a2 * mi;
        #pragma unroll
        for (int l = 0; l < LN; ++l) {
            kr[l] = fmaf(mr, Wr_o[l * FCN + j], kr[l]);
            ki[l] = fmaf(mi, Wi_o[l * FCN + j], ki[l]);
        }
    }
    *(reinterpret_cast<float4*>(o_kr) + b) = make_float4(kr[0], kr[1], kr[2], kr[3]);
    *(reinterpret_cast<float4*>(o_ki) + b) = make_float4(ki[0], ki[1], ki[2], ki[3]);
}

extern "C" void kernel_launch(void* const* d_in, const int* in_sizes, int n_in,
                              void* d_out, int out_size, void* d_ws, size_t ws_size,
                              hipStream_t stream) {
    const int n = in_sizes[0] / INN;   // batch size (524288, multiple of 64)
    const float* in_r   = (const float*)d_in[0];
    const float* in_i   = (const float*)d_in[1];
    const float* h_rr   = (const float*)d_in[2];
    const float* h_ir   = (const float*)d_in[3];
    const float* h_ri   = (const float*)d_in[4];
    const float* h_ii   = (const float*)d_in[5];
    const float* Wr_in  = (const float*)d_in[6];
    const float* br_in  = (const float*)d_in[7];
    const float* Wi_in  = (const float*)d_in[8];
    const float* bi_in  = (const float*)d_in[9];
    const float* a1p    = (const float*)d_in[10];
    const float* gr_Wih = (const float*)d_in[11];
    const float* gr_Whh = (const float*)d_in[12];
    const float* gr_bih = (const float*)d_in[13];
    const float* gr_bhh = (const float*)d_in[14];
    const float* gi_Wih = (const float*)d_in[15];
    const float* gi_Whh = (const float*)d_in[16];
    const float* gi_bih = (const float*)d_in[17];
    const float* gi_bhh = (const float*)d_in[18];
    const float* Wr_m   = (const float*)d_in[19];
    const float* br_m   = (const float*)d_in[20];
    const float* Wi_m   = (const float*)d_in[21];
    const float* bi_m   = (const float*)d_in[22];
    const float* a2p    = (const float*)d_in[23];
    const float* Wr_o   = (const float*)d_in[24];
    const float* br_o   = (const float*)d_in[25];
    const float* Wi_o   = (const float*)d_in[26];
    const float* bi_o   = (const float*)d_in[27];

    dim3 block(256);
    dim3 grid((n + 255) / 256);
    kgnet_kernel<<<grid, block, 0, stream>>>(
        in_r, in_i, h_rr, h_ir, h_ri, h_ii,
        Wr_in, br_in, Wi_in, bi_in, a1p,
        gr_Wih, gr_Whh, gr_bih, gr_bhh,
        gi_Wih, gi_Whh, gi_bih, gi_bhh,
        Wr_m, br_m, Wi_m, bi_m, a2p,
        Wr_o, br_o, Wi_o, bi_o,
        (float*)d_out, n);
}

// Round 12
// 623.575 us; speedup vs baseline: 1.6897x; 1.1580x over previous
//
#include <hip/hip_runtime.h>

// Problem dims (fixed by reference)
#define INN 9    // 2*L+1
#define FCN 18
#define HN  18
#define LN  4

__device__ __forceinline__ float rcp_f(float x) { return __builtin_amdgcn_rcpf(x); }
__device__ __forceinline__ float sigm(float x)  { return rcp_f(1.0f + __expf(-x)); }
__device__ __forceinline__ float tanh_f(float x) {
    float t = __expf(fminf(2.0f * x, 80.0f));
    return (t - 1.0f) * rcp_f(t + 1.0f);
}

// Coalesced float2 staging: 64 rows x 18 floats = 576 float2, 9 per lane.
// g must point at the wave's region start (8B-aligned: base*72 bytes).
__device__ __forceinline__ void stage2(float* __restrict__ buf, const float* __restrict__ g, int lane) {
    const float2* g2 = reinterpret_cast<const float2*>(g);
    float2* l2 = reinterpret_cast<float2*>(buf);
    #pragma unroll
    for (int t = 0; t < 9; ++t) l2[lane + 64 * t] = g2[lane + 64 * t];
}
__device__ __forceinline__ void store2(float* __restrict__ g, const float* __restrict__ buf, int lane) {
    float2* g2 = reinterpret_cast<float2*>(g);
    const float2* l2 = reinterpret_cast<const float2*>(buf);
    #pragma unroll
    for (int t = 0; t < 9; ++t) g2[lane + 64 * t] = l2[lane + 64 * t];
}

// Two GRU cells sharing one j-loop. h rows live in wave-private LDS (lA/lB point
// at this lane's 18-float row); slot j is read (h[j]) then overwritten in place
// with the cell output o[j] — the buffer morphs h -> F for the coalesced store.
// g[j] = oA + sign*oB folds immediately into the mask accumulator (no
// runtime-indexed register arrays -> no scratch).
__device__ __forceinline__ void cell_pair(
    const float* yA, const float* yB,            // [FCN] register arrays
    const float* hAreg, const float* hBreg,      // [HN] register arrays
    float* lA, float* lB,                        // LDS row ptrs (lane-private)
    const float* __restrict__ WihA, const float* __restrict__ WhhA,
    const float* __restrict__ bihA, const float* __restrict__ bhhA,
    const float* __restrict__ WihB, const float* __restrict__ WhhB,
    const float* __restrict__ bihB, const float* __restrict__ bhhB,
    const float* __restrict__ Wm,                // (FCN,HN) row-major, column j read
    float sign, float* macc)                     // [FCN] register accumulator
{
    #pragma unroll 1
    for (int j = 0; j < HN; ++j) {
        float aIr = bihA[j], aIz = bihA[HN + j], aIn = bihA[2 * HN + j];
        float aHr = bhhA[j], aHz = bhhA[HN + j], aHn = bhhA[2 * HN + j];
        float bIr = bihB[j], bIz = bihB[HN + j], bIn = bihB[2 * HN + j];
        float bHr = bhhB[j], bHz = bhhB[HN + j], bHn = bhhB[2 * HN + j];

        const float* wA0 = WihA + j * FCN;
        const float* wA1 = WihA + (HN + j) * FCN;
        const float* wA2 = WihA + (2 * HN + j) * FCN;
        const float* wB0 = WihB + j * FCN;
        const float* wB1 = WihB + (HN + j) * FCN;
        const float* wB2 = WihB + (2 * HN + j) * FCN;
        #pragma unroll
        for (int k = 0; k < FCN; ++k) {
            aIr = fmaf(yA[k], wA0[k], aIr);
            aIz = fmaf(yA[k], wA1[k], aIz);
            aIn = fmaf(yA[k], wA2[k], aIn);
            bIr = fmaf(yB[k], wB0[k], bIr);
            bIz = fmaf(yB[k], wB1[k], bIz);
            bIn = fmaf(yB[k], wB2[k], bIn);
        }

        const float* uA0 = WhhA + j * HN;
        const float* uA1 = WhhA + (HN + j) * HN;
        const float* uA2 = WhhA + (2 * HN + j) * HN;
        const float* uB0 = WhhB + j * HN;
        const float* uB1 = WhhB + (HN + j) * HN;
        const float* uB2 = WhhB + (2 * HN + j) * HN;
        #pragma unroll
        for (int k = 0; k < HN; ++k) {
            aHr = fmaf(hAreg[k], uA0[k], aHr);
            aHz = fmaf(hAreg[k], uA1[k], aHz);
            aHn = fmaf(hAreg[k], uA2[k], aHn);
            bHr = fmaf(hBreg[k], uB0[k], bHr);
            bHz = fmaf(hBreg[k], uB1[k], bHz);
            bHn = fmaf(hBreg[k], uB2[k], bHn);
        }

        float rA = sigm(aIr + aHr);
        float zA = sigm(aIz + aHz);
        float nA = tanh_f(aIn + rA * aHn);
        float hjA = lA[j];                        // LDS, runtime j: fine
        float oA = (1.0f - zA) * nA + zA * hjA;

        float rB = sigm(bIr + bHr);
        float zB = sigm(bIz + bHz);
        float nB = tanh_f(bIn + rB * bHn);
        float hjB = lB[j];
        float oB = (1.0f - zB) * nB + zB * hjB;

        lA[j] = oA;                               // in-place: h row becomes F row
        lB[j] = oB;

        float g = oA + sign * oB;                 // g_real (sign=-1) / g_imag (sign=+1)
        #pragma unroll
        for (int i = 0; i < FCN; ++i)
            macc[i] = fmaf(g, Wm[i * HN + j], macc[i]);
    }
}

// 1-wave blocks: LDS 9216 B/block -> up to 16 blocks/CU (theoretical 50% occ),
// double the 256-thread variant's measured residency. Per-wave code identical.
__global__ __launch_bounds__(64, 4) void kgnet_kernel(
    const float* __restrict__ in_r, const float* __restrict__ in_i,
    const float* __restrict__ h_rr, const float* __restrict__ h_ir,
    const float* __restrict__ h_ri, const float* __restrict__ h_ii,
    const float* __restrict__ Wr_in, const float* __restrict__ br_in,
    const float* __restrict__ Wi_in, const float* __restrict__ bi_in,
    const float* __restrict__ a1p,
    const float* __restrict__ gr_Wih, const float* __restrict__ gr_Whh,
    const float* __restrict__ gr_bih, const float* __restrict__ gr_bhh,
    const float* __restrict__ gi_Wih, const float* __restrict__ gi_Whh,
    const float* __restrict__ gi_bih, const float* __restrict__ gi_bhh,
    const float* __restrict__ Wr_m, const float* __restrict__ br_m,
    const float* __restrict__ Wi_m, const float* __restrict__ bi_m,
    const float* __restrict__ a2p,
    const float* __restrict__ Wr_o, const float* __restrict__ br_o,
    const float* __restrict__ Wi_o, const float* __restrict__ bi_o,
    float* __restrict__ out, int n)
{
    // Wave-private staging buffers; all LDS traffic within-wave -> no barriers.
    __shared__ float lds[2][64 * HN];

    const int lane = threadIdx.x;                 // block == one wave
    const int base = blockIdx.x * 64;
    if (base >= n) return;                        // n % 64 == 0
    const int b = base + lane;

    float* bufA = lds[0];
    float* bufB = lds[1];

    const float a1 = a1p[0];
    const float a2 = a2p[0];

    // ---- stage inputs coalesced into bufA: in_r at [0,576), in_i at [576,1152) ----
    {
        const float* gr_ = in_r + (size_t)base * INN;
        const float* gi_ = in_i + (size_t)base * INN;
        #pragma unroll
        for (int t = 0; t < INN; ++t) {
            bufA[lane + 64 * t]       = gr_[lane + 64 * t];
            bufA[576 + lane + 64 * t] = gi_[lane + 64 * t];
        }
    }

    // ---- input layer: yr/yi = prelu(x @ W_in.T + b_in) ----
    float yr[FCN], yi[FCN];
    {
        float xr[INN], xi[INN];
        const float* rowr = bufA + lane * INN;
        const float* rowi = bufA + 576 + lane * INN;
        #pragma unroll
        for (int k = 0; k < INN; ++k) { xr[k] = rowr[k]; xi[k] = rowi[k]; }
        #pragma unroll
        for (int j = 0; j < FCN; ++j) {
            float sr = br_in[j], si = bi_in[j];
            #pragma unroll
            for (int k = 0; k < INN; ++k) {
                sr = fmaf(xr[k], Wr_in[j * INN + k], sr);
                si = fmaf(xi[k], Wi_in[j * INN + k], si);
            }
            yr[j] = sr >= 0.0f ? sr : a1 * sr;
            yi[j] = si >= 0.0f ? si : a1 * si;
        }
    }

    // ---- output regions: [kr B*4][ki B*4][Frr B*18][Fir][Fri][Fii] ----
    const size_t B = (size_t)n;
    float* o_kr = out;
    float* o_ki = out + 4 * B;
    float* outF = out + 8 * B;
    const size_t woff = (size_t)base * HN;        // wave's F/h region offset (floats)

    float mr_acc[FCN], mi_acc[FCN];
    #pragma unroll
    for (int i = 0; i < FCN; ++i) { mr_acc[i] = 0.0f; mi_acc[i] = 0.0f; }

    float* lA = bufA + lane * HN;
    float* lB = bufB + lane * HN;

    // ---- pair 1: Frr (yr,h_rr,gr) & Fii (yi,h_ii,gi); g_real = Frr - Fii ----
    {
        stage2(bufA, h_rr + woff, lane);
        stage2(bufB, h_ii + woff, lane);
        float hA[HN], hB[HN];
        #pragma unroll
        for (int k = 0; k < HN; ++k) { hA[k] = lA[k]; hB[k] = lB[k]; }
        cell_pair(yr, yi, hA, hB, lA, lB,
                  gr_Wih, gr_Whh, gr_bih, gr_bhh,
                  gi_Wih, gi_Whh, gi_bih, gi_bhh,
                  Wr_m, -1.0f, mr_acc);
        store2(outF + 0 * B * HN + woff, bufA, lane);   // Frr
        store2(outF + 3 * B * HN + woff, bufB, lane);   // Fii
    }
    // ---- pair 2: Fir (yi,h_ir,gr) & Fri (yr,h_ri,gi); g_imag = Fir + Fri ----
    {
        stage2(bufA, h_ir + woff, lane);
        stage2(bufB, h_ri + woff, lane);
        float hA[HN], hB[HN];
        #pragma unroll
        for (int k = 0; k < HN; ++k) { hA[k] = lA[k]; hB[k] = lB[k]; }
        cell_pair(yi, yr, hA, hB, lA, lB,
                  gr_Wih, gr_Whh, gr_bih, gr_bhh,
                  gi_Wih, gi_Whh, gi_bih, gi_bhh,
                  Wi_m, +1.0f, mi_acc);
        store2(outF + 1 * B * HN + woff, bufA, lane);   // Fir
        store2(outF + 2 * B * HN + woff, bufB, lane);   // Fri
    }

    // ---- mask prelu + output layer ----
    float kr[LN], ki[LN];
    #pragma unroll
    for (int l = 0; l < LN; ++l) { kr[l] = br_o[l]; ki[l] = bi_o[l]; }
    #pragma unroll
    for (int j = 0; j < FCN; ++j) {
        float mr = mr_acc[j] + br_m[j];
        mr = mr >= 0.0f ? mr : a2 * mr;
        float mi = mi_acc[j] + bi_m[j];
        mi = mi >= 0.0f ? mi : a2 * mi;
        #pragma unroll
        for (int l = 0; l < LN; ++l) {
            kr[l] = fmaf(mr, Wr_o[l * FCN + j], kr[l]);
            ki[l] = fmaf(mi, Wi_o[l * FCN + j], ki[l]);
        }
    }
    *(reinterpret_cast<float4*>(o_kr) + b) = make_float4(kr[0], kr[1], kr[2], kr[3]);
    *(reinterpret_cast<float4*>(o_ki) + b) = make_float4(ki[0], ki[1], ki[2], ki[3]);
}

extern "C" void kernel_launch(void* const* d_in, const int* in_sizes, int n_in,
                              void* d_out, int out_size, void* d_ws, size_t ws_size,
                              hipStream_t stream) {
    const int n = in_sizes[0] / INN;   // batch size (524288, multiple of 64)
    const float* in_r   = (const float*)d_in[0];
    const float* in_i   = (const float*)d_in[1];
    const float* h_rr   = (const float*)d_in[2];
    const float* h_ir   = (const float*)d_in[3];
    const float* h_ri   = (const float*)d_in[4];
    const float* h_ii   = (const float*)d_in[5];
    const float* Wr_in  = (const float*)d_in[6];
    const float* br_in  = (const float*)d_in[7];
    const float* Wi_in  = (const float*)d_in[8];
    const float* bi_in  = (const float*)d_in[9];
    const float* a1p    = (const float*)d_in[10];
    const float* gr_Wih = (const float*)d_in[11];
    const float* gr_Whh = (const float*)d_in[12];
    const float* gr_bih = (const float*)d_in[13];
    const float* gr_bhh = (const float*)d_in[14];
    const float* gi_Wih = (const float*)d_in[15];
    const float* gi_Whh = (const float*)d_in[16];
    const float* gi_bih = (const float*)d_in[17];
    const float* gi_bhh = (const float*)d_in[18];
    const float* Wr_m   = (const float*)d_in[19];
    const float* br_m   = (const float*)d_in[20];
    const float* Wi_m   = (const float*)d_in[21];
    const float* bi_m   = (const float*)d_in[22];
    const float* a2p    = (const float*)d_in[23];
    const float* Wr_o   = (const float*)d_in[24];
    const float* br_o   = (const float*)d_in[25];
    const float* Wi_o   = (const float*)d_in[26];
    const float* bi_o   = (const float*)d_in[27];

    dim3 block(64);
    dim3 grid((n + 63) / 64);
    kgnet_kernel<<<grid, block, 0, stream>>>(
        in_r, in_i, h_rr, h_ir, h_ri, h_ii,
        Wr_in, br_in, Wi_in, bi_in, a1p,
        gr_Wih, gr_Whh, gr_bih, gr_bhh,
        gi_Wih, gi_Whh, gi_bih, gi_bhh,
        Wr_m, br_m, Wi_m, bi_m, a2p,
        Wr_o, br_o, Wi_o, bi_o,
        (float*)d_out, n);
}